// Round 1
// baseline (1060.396 us; speedup 1.0000x reference)
//
#include <hip/hip_runtime.h>
#include <hip/hip_bf16.h>

typedef __attribute__((ext_vector_type(8))) short short8;
typedef __attribute__((ext_vector_type(4))) float f32x4;

#define NN 50000
#define NE 600000

__device__ __forceinline__ unsigned short f32_bf16(float f) {
  unsigned u = __float_as_uint(f);
  unsigned r = u + 0x7FFFu + ((u >> 16) & 1u);
  return (unsigned short)(r >> 16);
}

// ---------------- transpose + convert W [K][N] f32 -> WT [N][Kpad] bf16 (zero pad) ----
__global__ void transpose_bf16_kernel(const float* __restrict__ W, unsigned short* __restrict__ WT,
                                      int K, int N, int Kpad) {
  int idx = blockIdx.x * 256 + threadIdx.x;
  if (idx >= N * Kpad) return;
  int n = idx / Kpad, k = idx % Kpad;
  float v = (k < K) ? W[(size_t)k * N + n] : 0.f;
  WT[idx] = f32_bf16(v);
}

// ---------------- degree (weighted) + count per dst ----------------
__global__ void deg_cnt_kernel(const int* __restrict__ ei, const float* __restrict__ ew,
                               float* __restrict__ deg, int* __restrict__ cnt, int E) {
  int e = blockIdx.x * 256 + threadIdx.x;
  if (e >= E) return;
  int d = ei[E + e];  // dst row of ei[2][E]
  atomicAdd(&deg[d], ew[e]);
  atomicAdd(&cnt[d], 1);
}

__global__ void dinv_kernel(const float* __restrict__ deg, float* __restrict__ dinv, int n) {
  int i = blockIdx.x * 256 + threadIdx.x;
  if (i >= n) return;
  float d = deg[i] + 1.0f;  // + self loop weight 1
  dinv[i] = (d > 0.f) ? rsqrtf(d) : 0.f;
}

// ---------------- 3-pass exclusive scan of cnt -> csr_off, cursor ----------------
__global__ void scan1_kernel(const int* __restrict__ cnt, int* __restrict__ partial,
                             int* __restrict__ bsums, int n) {
  __shared__ int sd[256];
  int i = blockIdx.x * 256 + threadIdx.x;
  int v = (i < n) ? cnt[i] : 0;
  sd[threadIdx.x] = v;
  __syncthreads();
  for (int o = 1; o < 256; o <<= 1) {
    int t = (threadIdx.x >= o) ? sd[threadIdx.x - o] : 0;
    __syncthreads();
    sd[threadIdx.x] += t;
    __syncthreads();
  }
  if (i < n) partial[i] = sd[threadIdx.x];  // inclusive
  if (threadIdx.x == 255) bsums[blockIdx.x] = sd[255];
}

__global__ void scan2_kernel(int* __restrict__ bsums, int nb) {
  __shared__ int sd[256];
  int v = (threadIdx.x < nb) ? bsums[threadIdx.x] : 0;
  sd[threadIdx.x] = v;
  __syncthreads();
  for (int o = 1; o < 256; o <<= 1) {
    int t = (threadIdx.x >= o) ? sd[threadIdx.x - o] : 0;
    __syncthreads();
    sd[threadIdx.x] += t;
    __syncthreads();
  }
  if (threadIdx.x < nb) bsums[threadIdx.x] = sd[threadIdx.x] - v;  // exclusive
}

__global__ void scan3_kernel(const int* __restrict__ partial, const int* __restrict__ cnt,
                             const int* __restrict__ bsums, int* __restrict__ off,
                             int* __restrict__ cursor, int n, int E) {
  int i = blockIdx.x * 256 + threadIdx.x;
  if (i < n) {
    int ex = partial[i] - cnt[i] + bsums[blockIdx.x];
    off[i] = ex;
    cursor[i] = ex;
  }
  if (i == 0) off[n] = E;
}

// ---------------- bucket edges into CSR (by dst), norm precomputed ----------------
__global__ void bucket_kernel(const int* __restrict__ ei, const float* __restrict__ ew,
                              const float* __restrict__ dinv, int* __restrict__ cursor,
                              int* __restrict__ csrc, float* __restrict__ cw, int E) {
  int e = blockIdx.x * 256 + threadIdx.x;
  if (e >= E) return;
  int s = ei[e], d = ei[E + e];
  int pos = atomicAdd(&cursor[d], 1);
  csrc[pos] = s;
  cw[pos] = dinv[s] * ew[e] * dinv[d];
}

// ---------------- bf16 MFMA GEMM: C[MxBN] = A[MxK] * B[KxBN], BT = B^T [BN][Kpad] bf16 ---
template <int BN, bool EPI>
__global__ __launch_bounds__(256) void gemm_kernel(const float* __restrict__ A,
                                                   const unsigned short* __restrict__ BT,
                                                   const float* __restrict__ bias,
                                                   float* __restrict__ C, int M, int K,
                                                   int Kpad, int ldc) {
  constexpr int BM = 128, BK = 32;
  constexpr int LDS_W = BK + 8;  // 40 bf16 = 80B row stride (bank-friendly)
  __shared__ __align__(16) unsigned short As[BM * LDS_W];
  __shared__ __align__(16) unsigned short Bs[BN * LDS_W];
  const int tid = threadIdx.x;
  const int m0 = blockIdx.x * BM;
  const int wid = tid >> 6, lane = tid & 63;
  constexpr int WR = (BN == 128) ? 2 : 4;
  constexpr int WC = (BN == 128) ? 2 : 1;
  constexpr int WTM = BM / WR, WTN = BN / WC;
  constexpr int FM = WTM / 16, FN = WTN / 16;
  const int wr = wid / WC, wc = wid % WC;
  const int rowbase = wr * WTM, colbase = wc * WTN;
  const int lrow = lane & 15, lk = lane >> 4;

  f32x4 acc[FM][FN] = {};

  const int kTiles = Kpad / BK;
  for (int kt = 0; kt < kTiles; ++kt) {
    const int k0 = kt * BK;
    // stage A tile (BM x BK) f32 -> bf16, 1024 float4s, 4 per thread
#pragma unroll
    for (int p = 0; p < 4; ++p) {
      int f = tid + p * 256;
      int row = f >> 3, c4 = f & 7;
      int gr = m0 + row, gk = k0 + c4 * 4;
      float4 v = make_float4(0.f, 0.f, 0.f, 0.f);
      if (gr < M && gk < K) v = *(const float4*)(A + (size_t)gr * K + gk);
      unsigned a0 = (unsigned)f32_bf16(v.x) | ((unsigned)f32_bf16(v.y) << 16);
      unsigned a1 = (unsigned)f32_bf16(v.z) | ((unsigned)f32_bf16(v.w) << 16);
      *reinterpret_cast<uint2*>(&As[row * LDS_W + c4 * 4]) = make_uint2(a0, a1);
    }
    // stage B tile (BN x BK) from BT bf16 (already padded): 16B chunks
#pragma unroll
    for (int p = 0; p < BN / 64; ++p) {
      int f = tid + p * 256;
      int n = f >> 2, c8 = f & 3;
      short8 v = *(const short8*)(BT + (size_t)n * Kpad + k0 + c8 * 8);
      *reinterpret_cast<short8*>(&Bs[n * LDS_W + c8 * 8]) = v;
    }
    __syncthreads();
    short8 af[FM], bf[FN];
#pragma unroll
    for (int i = 0; i < FM; ++i)
      af[i] = *reinterpret_cast<const short8*>(&As[(rowbase + i * 16 + lrow) * LDS_W + lk * 8]);
#pragma unroll
    for (int j = 0; j < FN; ++j)
      bf[j] = *reinterpret_cast<const short8*>(&Bs[(colbase + j * 16 + lrow) * LDS_W + lk * 8]);
#pragma unroll
    for (int i = 0; i < FM; ++i)
#pragma unroll
      for (int j = 0; j < FN; ++j)
        acc[i][j] = __builtin_amdgcn_mfma_f32_16x16x32_bf16(af[i], bf[j], acc[i][j], 0, 0, 0);
    __syncthreads();
  }

#pragma unroll
  for (int i = 0; i < FM; ++i) {
#pragma unroll
    for (int j = 0; j < FN; ++j) {
#pragma unroll
      for (int q = 0; q < 4; ++q) {
        int row = m0 + rowbase + i * 16 + lk * 4 + q;
        int col = colbase + j * 16 + lrow;
        if (row < M) {
          float v = acc[i][j][q];
          if (EPI) v = fmaxf(v + bias[col], 0.f);
          C[(size_t)row * ldc + col] = v;
        }
      }
    }
  }
}

// ---------------- CSR gather aggregation: out[i] = relu(sum_j x[src]*w + x[i]*dinv^2 + b) --
template <int H>
__global__ void agg_kernel(const float* __restrict__ x, const float* __restrict__ dinv,
                           const int* __restrict__ off, const int* __restrict__ src,
                           const float* __restrict__ w, const float* __restrict__ bias,
                           float* __restrict__ out, int ldo, int coff, int n) {
  int wid = blockIdx.x * 4 + (threadIdx.x >> 6);
  if (wid >= n) return;
  int lane = threadIdx.x & 63;
  const int i = wid;
  float di = dinv[i];
  constexpr int PER = H / 64;
  float acc[PER];
#pragma unroll
  for (int p = 0; p < PER; ++p) acc[p] = x[(size_t)i * H + lane + p * 64] * (di * di);
  int s = off[i], e = off[i + 1];
  for (int t = s; t < e; ++t) {
    int sj = src[t];
    float wt = w[t];
#pragma unroll
    for (int p = 0; p < PER; ++p) acc[p] += x[(size_t)sj * H + lane + p * 64] * wt;
  }
#pragma unroll
  for (int p = 0; p < PER; ++p) {
    int c = lane + p * 64;
    out[(size_t)i * ldo + coff + c] = fmaxf(acc[p] + bias[c], 0.f);
  }
}

// ---------------- pred: out[i][0..1] = fused[i] @ W_pred + b_pred ----------------
__global__ void pred_kernel(const float* __restrict__ fused, const float* __restrict__ Wp,
                            const float* __restrict__ bp, float* __restrict__ out, int n) {
  __shared__ float ws_[128];
  __shared__ float bs_[2];
  if (threadIdx.x < 128) ws_[threadIdx.x] = Wp[threadIdx.x];
  if (threadIdx.x < 2) bs_[threadIdx.x] = bp[threadIdx.x];
  __syncthreads();
  int i = blockIdx.x * 256 + threadIdx.x;
  if (i >= n) return;
  float a0 = bs_[0], a1 = bs_[1];
  const float4* row = reinterpret_cast<const float4*>(fused + (size_t)i * 64);
#pragma unroll
  for (int q = 0; q < 16; ++q) {
    float4 f = row[q];
    int k = q * 4;
    a0 += f.x * ws_[(k + 0) * 2] + f.y * ws_[(k + 1) * 2] + f.z * ws_[(k + 2) * 2] +
          f.w * ws_[(k + 3) * 2];
    a1 += f.x * ws_[(k + 0) * 2 + 1] + f.y * ws_[(k + 1) * 2 + 1] + f.z * ws_[(k + 2) * 2 + 1] +
          f.w * ws_[(k + 3) * 2 + 1];
  }
  out[(size_t)i * 2 + 0] = a0;
  out[(size_t)i * 2 + 1] = a1;
}

extern "C" void kernel_launch(void* const* d_in, const int* in_sizes, int n_in, void* d_out,
                              int out_size, void* d_ws, size_t ws_size, hipStream_t stream) {
  const int N = NN, E = NE;
  const int Ds[3] = {1000, 1000, 500};
  const int H1 = 128, H2 = 64, CH = 192;

  char* p = (char*)d_ws;
  auto carve = [&](size_t bytes) {
    void* r = (void*)p;
    p += (bytes + 255) & ~(size_t)255;
    return r;
  };

  unsigned short* w1t[3];
  int kpad1[3];
  for (int b = 0; b < 3; ++b) {
    kpad1[b] = (Ds[b] + 31) & ~31;
    w1t[b] = (unsigned short*)carve((size_t)H1 * kpad1[b] * 2);
  }
  unsigned short* w2t[3];
  for (int b = 0; b < 3; ++b) w2t[b] = (unsigned short*)carve((size_t)H2 * 128 * 2);
  unsigned short* wft = (unsigned short*)carve((size_t)H2 * 192 * 2);

  float* deg = (float*)carve((size_t)N * 4);
  int* cnt = (int*)carve((size_t)N * 4);
  float* dinv = (float*)carve((size_t)N * 4);
  int* csr_off = (int*)carve((size_t)(N + 1) * 4);
  int* cursor = (int*)carve((size_t)N * 4);
  int* partial = (int*)carve((size_t)N * 4);
  int* bsums = (int*)carve(256 * 4);
  int* csr_src = (int*)carve((size_t)E * 4);
  float* csr_w = (float*)carve((size_t)E * 4);
  float* x1 = (float*)carve((size_t)N * H1 * 4);  // reused as x2 and fused
  float* h1 = (float*)carve((size_t)N * H1 * 4);
  float* comb = (float*)carve((size_t)N * CH * 4);
  float* x2 = x1;
  float* fused = x1;

  const int gx = (N + 127) / 128;      // 391
  const int nb = (N + 255) / 256;      // 196
  const int eb = (E + 255) / 256;      // 2344

  // one-time weight transposes (bf16)
  for (int b = 0; b < 3; ++b) {
    const float* W1 = (const float*)d_in[b * 7 + 3];
    int tot = H1 * kpad1[b];
    transpose_bf16_kernel<<<(tot + 255) / 256, 256, 0, stream>>>(W1, w1t[b], Ds[b], H1, kpad1[b]);
    const float* W2 = (const float*)d_in[b * 7 + 5];
    transpose_bf16_kernel<<<(H2 * 128 + 255) / 256, 256, 0, stream>>>(W2, w2t[b], 128, H2, 128);
  }
  transpose_bf16_kernel<<<(H2 * 192 + 255) / 256, 256, 0, stream>>>((const float*)d_in[21], wft,
                                                                    192, H2, 192);

  for (int b = 0; b < 3; ++b) {
    const float* feat = (const float*)d_in[b * 7 + 0];
    const int* ei = (const int*)d_in[b * 7 + 1];
    const float* ew = (const float*)d_in[b * 7 + 2];
    const float* b1 = (const float*)d_in[b * 7 + 4];
    const float* b2 = (const float*)d_in[b * 7 + 6];

    hipMemsetAsync(deg, 0, (size_t)N * 4, stream);
    hipMemsetAsync(cnt, 0, (size_t)N * 4, stream);
    deg_cnt_kernel<<<eb, 256, 0, stream>>>(ei, ew, deg, cnt, E);
    dinv_kernel<<<nb, 256, 0, stream>>>(deg, dinv, N);
    scan1_kernel<<<nb, 256, 0, stream>>>(cnt, partial, bsums, N);
    scan2_kernel<<<1, 256, 0, stream>>>(bsums, nb);
    scan3_kernel<<<nb, 256, 0, stream>>>(partial, cnt, bsums, csr_off, cursor, N, E);
    bucket_kernel<<<eb, 256, 0, stream>>>(ei, ew, dinv, cursor, csr_src, csr_w, E);

    gemm_kernel<128, false><<<gx, 256, 0, stream>>>(feat, w1t[b], nullptr, x1, N, Ds[b],
                                                    kpad1[b], H1);
    agg_kernel<128><<<(N + 3) / 4, 256, 0, stream>>>(x1, dinv, csr_off, csr_src, csr_w, b1, h1,
                                                     H1, 0, N);
    gemm_kernel<64, false><<<gx, 256, 0, stream>>>(h1, w2t[b], nullptr, x2, N, H1, H1, H2);
    agg_kernel<64><<<(N + 3) / 4, 256, 0, stream>>>(x2, dinv, csr_off, csr_src, csr_w, b2, comb,
                                                    CH, b * 64, N);
  }

  gemm_kernel<64, true><<<gx, 256, 0, stream>>>(comb, wft, (const float*)d_in[22], fused, N, CH,
                                                CH, H2);
  pred_kernel<<<nb, 256, 0, stream>>>(fused, (const float*)d_in[23], (const float*)d_in[24],
                                      (float*)d_out, N);
}

// Round 2
// 842.608 us; speedup vs baseline: 1.2585x; 1.2585x over previous
//
#include <hip/hip_runtime.h>
#include <hip/hip_bf16.h>

typedef __attribute__((ext_vector_type(8))) short short8;
typedef __attribute__((ext_vector_type(4))) float f32x4;

#define NN 50000
#define NE 600000

__device__ __forceinline__ unsigned short f32_bf16(float f) {
  unsigned u = __float_as_uint(f);
  unsigned r = u + 0x7FFFu + ((u >> 16) & 1u);
  return (unsigned short)(r >> 16);
}
__device__ __forceinline__ float bf_lo(unsigned v) { return __uint_as_float(v << 16); }
__device__ __forceinline__ float bf_hi(unsigned v) { return __uint_as_float(v & 0xFFFF0000u); }

// ---------------- fused transpose of all 7 weights: W[K][N] f32 -> WT[N][Kpad] bf16 ----
struct TransDesc { const float* src; unsigned short* dst; int K, Nn, Kpad, base; };
struct TransArgs { TransDesc d[7]; int total; };

__global__ void transpose_all_kernel(TransArgs a) {
  int idx = blockIdx.x * 256 + threadIdx.x;
  if (idx >= a.total) return;
  int s = 0;
#pragma unroll
  for (int q = 1; q < 7; ++q)
    if (idx >= a.d[q].base) s = q;
  TransDesc t = a.d[s];
  int off = idx - t.base;
  int n = off / t.Kpad, k = off % t.Kpad;
  float v = (k < t.K) ? t.src[(size_t)k * t.Nn + n] : 0.f;
  t.dst[off] = f32_bf16(v);
}

// ---------------- batched CSR build across 3 branches ----------------
struct EdgeArgs { const int* ei[3]; const float* ew[3]; };

__global__ void deg_cnt_kernel(EdgeArgs ea, float* __restrict__ deg3, int* __restrict__ cnt3,
                               int E, int bpb) {
  int b = blockIdx.x / bpb;
  int e = (blockIdx.x % bpb) * 256 + threadIdx.x;
  if (e >= E) return;
  const int* ei = ea.ei[b];
  int d = ei[E + e];
  atomicAdd(&deg3[b * NN + d], ea.ew[b][e]);
  atomicAdd(&cnt3[b * NN + d], 1);
}

__global__ void dinv_kernel(const float* __restrict__ deg3, float* __restrict__ dinv3, int tot) {
  int i = blockIdx.x * 256 + threadIdx.x;
  if (i >= tot) return;
  float d = deg3[i] + 1.0f;
  dinv3[i] = (d > 0.f) ? rsqrtf(d) : 0.f;
}

__global__ void scan1_kernel(const int* __restrict__ cnt3, int* __restrict__ partial3,
                             int* __restrict__ bsums3, int n, int bpb) {
  __shared__ int sd[256];
  int b = blockIdx.x / bpb, blk = blockIdx.x % bpb;
  int i = blk * 256 + threadIdx.x;
  int v = (i < n) ? cnt3[b * NN + i] : 0;
  sd[threadIdx.x] = v;
  __syncthreads();
  for (int o = 1; o < 256; o <<= 1) {
    int t = (threadIdx.x >= o) ? sd[threadIdx.x - o] : 0;
    __syncthreads();
    sd[threadIdx.x] += t;
    __syncthreads();
  }
  if (i < n) partial3[b * NN + i] = sd[threadIdx.x];
  if (threadIdx.x == 255) bsums3[b * 256 + blk] = sd[255];
}

__global__ void scan2_kernel(int* __restrict__ bsums3, int nb) {
  __shared__ int sd[256];
  int b = blockIdx.x;
  int v = (threadIdx.x < nb) ? bsums3[b * 256 + threadIdx.x] : 0;
  sd[threadIdx.x] = v;
  __syncthreads();
  for (int o = 1; o < 256; o <<= 1) {
    int t = (threadIdx.x >= o) ? sd[threadIdx.x - o] : 0;
    __syncthreads();
    sd[threadIdx.x] += t;
    __syncthreads();
  }
  if (threadIdx.x < nb) bsums3[b * 256 + threadIdx.x] = sd[threadIdx.x] - v;
}

__global__ void scan3_kernel(const int* __restrict__ partial3, const int* __restrict__ cnt3,
                             const int* __restrict__ bsums3, int* __restrict__ off3,
                             int* __restrict__ cursor3, int n, int E, int bpb) {
  int b = blockIdx.x / bpb, blk = blockIdx.x % bpb;
  int i = blk * 256 + threadIdx.x;
  if (i < n) {
    int ex = partial3[b * NN + i] - cnt3[b * NN + i] + bsums3[b * 256 + blk];
    off3[b * (NN + 1) + i] = ex;
    cursor3[b * NN + i] = ex;
  }
  if (i == 0) off3[b * (NN + 1) + n] = E;
}

__global__ void bucket_kernel(EdgeArgs ea, const float* __restrict__ dinv3,
                              int* __restrict__ cursor3, int* __restrict__ csrc3,
                              float* __restrict__ cw3, int E, int bpb) {
  int b = blockIdx.x / bpb;
  int e = (blockIdx.x % bpb) * 256 + threadIdx.x;
  if (e >= E) return;
  const int* ei = ea.ei[b];
  int s = ei[e], d = ei[E + e];
  int pos = atomicAdd(&cursor3[b * NN + d], 1);
  csrc3[b * NE + pos] = s;
  cw3[b * NE + pos] = dinv3[b * NN + s] * ea.ew[b][e] * dinv3[b * NN + d];
}

// ---------------- bf16 MFMA GEMM with register prefetch, BM=64 ----------------
template <int BN, bool ABF16, bool CBF16, bool EPI>
__global__ __launch_bounds__(256) void gemm_kernel(const void* __restrict__ Av,
                                                   const unsigned short* __restrict__ BT,
                                                   const float* __restrict__ bias,
                                                   void* __restrict__ Cv, int M, int K,
                                                   int Kpad, int ldc) {
  constexpr int BM = 64, BK = 32, LW = BK + 8;
  __shared__ __align__(16) unsigned short As[BM * LW];
  __shared__ __align__(16) unsigned short Bs[BN * LW];
  const int tid = threadIdx.x;
  const int m0 = blockIdx.x * BM;
  const int wid = tid >> 6, lane = tid & 63;
  constexpr int WC = (BN == 128) ? 2 : 1;
  constexpr int WTM = (BN == 128) ? 32 : 16;
  constexpr int FM = WTM / 16;
  constexpr int FN = 4;
  const int wr = wid / WC, wc = wid % WC;
  const int rowbase = wr * WTM, colbase = wc * 64;
  const int lrow = lane & 15, lk = lane >> 4;

  const float* Af = (const float*)Av;
  const unsigned short* Ah = (const unsigned short*)Av;

  f32x4 acc[FM][FN] = {};

  float4 arf[2];
  short8 arh;
  short8 brr[BN / 64];

  const int nt = Kpad / BK;

  auto loadA = [&](int k0) {
    if (ABF16) {
      int row = tid >> 2, c8 = tid & 3;
      int gr = m0 + row;
      if (gr >= M) gr = M - 1;
      arh = *(const short8*)(Ah + (size_t)gr * K + k0 + c8 * 8);
    } else {
#pragma unroll
      for (int p = 0; p < 2; ++p) {
        int f = tid + p * 256;
        int row = f >> 3, c4 = f & 7;
        int gr = m0 + row;
        if (gr >= M) gr = M - 1;
        int gk = k0 + c4 * 4;
        float4 v = make_float4(0.f, 0.f, 0.f, 0.f);
        const float* base = Af + (size_t)gr * K + gk;
        if (gk + 4 <= K) {
          v = *(const float4*)base;
        } else {
          if (gk + 0 < K) v.x = base[0];
          if (gk + 1 < K) v.y = base[1];
          if (gk + 2 < K) v.z = base[2];
          if (gk + 3 < K) v.w = base[3];
        }
        arf[p] = v;
      }
    }
  };
  auto loadB = [&](int k0) {
#pragma unroll
    for (int p = 0; p < BN / 64; ++p) {
      int f = tid + p * 256;
      int n = f >> 2, c8 = f & 3;
      brr[p] = *(const short8*)(BT + (size_t)n * Kpad + k0 + c8 * 8);
    }
  };
  auto storeAB = [&]() {
    if (ABF16) {
      int row = tid >> 2, c8 = tid & 3;
      *reinterpret_cast<short8*>(&As[row * LW + c8 * 8]) = arh;
    } else {
#pragma unroll
      for (int p = 0; p < 2; ++p) {
        int f = tid + p * 256;
        int row = f >> 3, c4 = f & 7;
        unsigned a0 = (unsigned)f32_bf16(arf[p].x) | ((unsigned)f32_bf16(arf[p].y) << 16);
        unsigned a1 = (unsigned)f32_bf16(arf[p].z) | ((unsigned)f32_bf16(arf[p].w) << 16);
        *reinterpret_cast<uint2*>(&As[row * LW + c4 * 4]) = make_uint2(a0, a1);
      }
    }
#pragma unroll
    for (int p = 0; p < BN / 64; ++p) {
      int f = tid + p * 256;
      int n = f >> 2, c8 = f & 3;
      *reinterpret_cast<short8*>(&Bs[n * LW + c8 * 8]) = brr[p];
    }
  };

  loadA(0);
  loadB(0);
  for (int kt = 0; kt < nt; ++kt) {
    if (kt) __syncthreads();
    storeAB();
    __syncthreads();
    if (kt + 1 < nt) {
      loadA((kt + 1) * BK);
      loadB((kt + 1) * BK);
    }
    short8 af[FM], bf[FN];
#pragma unroll
    for (int i = 0; i < FM; ++i)
      af[i] = *reinterpret_cast<const short8*>(&As[(rowbase + i * 16 + lrow) * LW + lk * 8]);
#pragma unroll
    for (int j = 0; j < FN; ++j)
      bf[j] = *reinterpret_cast<const short8*>(&Bs[(colbase + j * 16 + lrow) * LW + lk * 8]);
#pragma unroll
    for (int i = 0; i < FM; ++i)
#pragma unroll
      for (int j = 0; j < FN; ++j)
        acc[i][j] = __builtin_amdgcn_mfma_f32_16x16x32_bf16(af[i], bf[j], acc[i][j], 0, 0, 0);
  }

#pragma unroll
  for (int i = 0; i < FM; ++i) {
#pragma unroll
    for (int j = 0; j < FN; ++j) {
#pragma unroll
      for (int q = 0; q < 4; ++q) {
        int row = m0 + rowbase + i * 16 + lk * 4 + q;
        int col = colbase + j * 16 + lrow;
        if (row < M) {
          float v = acc[i][j][q];
          if (EPI) v = fmaxf(v + bias[col], 0.f);
          if (CBF16)
            ((unsigned short*)Cv)[(size_t)row * ldc + col] = f32_bf16(v);
          else
            ((float*)Cv)[(size_t)row * ldc + col] = v;
        }
      }
    }
  }
}

// ---------------- CSR gather aggregation, bf16 in / bf16 out, bias+relu ----------------
__global__ void agg128_kernel(const unsigned short* __restrict__ x, const float* __restrict__ dinv,
                              const int* __restrict__ off, const int* __restrict__ src,
                              const float* __restrict__ w, const float* __restrict__ bias,
                              unsigned short* __restrict__ out, int n) {
  int i = blockIdx.x * 4 + (threadIdx.x >> 6);
  if (i >= n) return;
  int lane = threadIdx.x & 63;
  float di = dinv[i];
  unsigned sv = *(const unsigned*)(x + (size_t)i * 128 + lane * 2);
  float w0 = di * di;
  float acc0 = bf_lo(sv) * w0, acc1 = bf_hi(sv) * w0;
  int s = off[i], e = off[i + 1];
  for (int t = s; t < e; ++t) {
    int sj = src[t];
    float wt = w[t];
    unsigned v = *(const unsigned*)(x + (size_t)sj * 128 + lane * 2);
    acc0 += bf_lo(v) * wt;
    acc1 += bf_hi(v) * wt;
  }
  acc0 = fmaxf(acc0 + bias[lane * 2], 0.f);
  acc1 = fmaxf(acc1 + bias[lane * 2 + 1], 0.f);
  unsigned o = (unsigned)f32_bf16(acc0) | ((unsigned)f32_bf16(acc1) << 16);
  *(unsigned*)(out + (size_t)i * 128 + lane * 2) = o;
}

__global__ void agg64_kernel(const unsigned short* __restrict__ x, const float* __restrict__ dinv,
                             const int* __restrict__ off, const int* __restrict__ src,
                             const float* __restrict__ w, const float* __restrict__ bias,
                             unsigned short* __restrict__ out, int ldo, int coff, int n) {
  int i = blockIdx.x * 4 + (threadIdx.x >> 6);
  if (i >= n) return;
  int lane = threadIdx.x & 63;
  int half = lane >> 5, l2 = (lane & 31) * 2;
  float acc0 = 0.f, acc1 = 0.f;
  if (half == 0) {
    float di = dinv[i];
    unsigned sv = *(const unsigned*)(x + (size_t)i * 64 + l2);
    float w0 = di * di;
    acc0 = bf_lo(sv) * w0;
    acc1 = bf_hi(sv) * w0;
  }
  int s = off[i], e = off[i + 1];
  for (int t = s + half; t < e; t += 2) {
    int sj = src[t];
    float wt = w[t];
    unsigned v = *(const unsigned*)(x + (size_t)sj * 64 + l2);
    acc0 += bf_lo(v) * wt;
    acc1 += bf_hi(v) * wt;
  }
  acc0 += __shfl_xor(acc0, 32);
  acc1 += __shfl_xor(acc1, 32);
  if (half == 0) {
    acc0 = fmaxf(acc0 + bias[l2], 0.f);
    acc1 = fmaxf(acc1 + bias[l2 + 1], 0.f);
    unsigned o = (unsigned)f32_bf16(acc0) | ((unsigned)f32_bf16(acc1) << 16);
    *(unsigned*)(out + (size_t)i * ldo + coff + l2) = o;
  }
}

// ---------------- pred: out[i][0..1] = fused_bf16[i] @ W_pred + b_pred ----------------
__global__ void pred_kernel(const unsigned short* __restrict__ fused, const float* __restrict__ Wp,
                            const float* __restrict__ bp, float* __restrict__ out, int n) {
  __shared__ float ws_[128];
  __shared__ float bs_[2];
  if (threadIdx.x < 128) ws_[threadIdx.x] = Wp[threadIdx.x];
  if (threadIdx.x < 2) bs_[threadIdx.x] = bp[threadIdx.x];
  __syncthreads();
  int i = blockIdx.x * 256 + threadIdx.x;
  if (i >= n) return;
  float a0 = bs_[0], a1 = bs_[1];
  const uint2* row = reinterpret_cast<const uint2*>(fused + (size_t)i * 64);
#pragma unroll
  for (int q = 0; q < 16; ++q) {
    uint2 u = row[q];
    float f0 = bf_lo(u.x), f1 = bf_hi(u.x), f2 = bf_lo(u.y), f3 = bf_hi(u.y);
    int k = q * 4;
    a0 += f0 * ws_[k * 2] + f1 * ws_[(k + 1) * 2] + f2 * ws_[(k + 2) * 2] + f3 * ws_[(k + 3) * 2];
    a1 += f0 * ws_[k * 2 + 1] + f1 * ws_[(k + 1) * 2 + 1] + f2 * ws_[(k + 2) * 2 + 1] +
          f3 * ws_[(k + 3) * 2 + 1];
  }
  out[(size_t)i * 2 + 0] = a0;
  out[(size_t)i * 2 + 1] = a1;
}

extern "C" void kernel_launch(void* const* d_in, const int* in_sizes, int n_in, void* d_out,
                              int out_size, void* d_ws, size_t ws_size, hipStream_t stream) {
  const int N = NN, E = NE;
  const int Ds[3] = {1000, 1000, 500};
  const int H1 = 128, H2 = 64, CH = 192;

  char* p = (char*)d_ws;
  auto carve = [&](size_t bytes) {
    void* r = (void*)p;
    p += (bytes + 255) & ~(size_t)255;
    return r;
  };

  unsigned short* w1t[3];
  int kpad1[3];
  for (int b = 0; b < 3; ++b) {
    kpad1[b] = (Ds[b] + 31) & ~31;
    w1t[b] = (unsigned short*)carve((size_t)H1 * kpad1[b] * 2);
  }
  unsigned short* w2t[3];
  for (int b = 0; b < 3; ++b) w2t[b] = (unsigned short*)carve((size_t)H2 * 128 * 2);
  unsigned short* wft = (unsigned short*)carve((size_t)H2 * 192 * 2);

  float* deg3 = (float*)carve((size_t)3 * N * 4);
  int* cnt3 = (int*)carve((size_t)3 * N * 4);
  float* dinv3 = (float*)carve((size_t)3 * N * 4);
  int* partial3 = (int*)carve((size_t)3 * N * 4);
  int* bsums3 = (int*)carve((size_t)3 * 256 * 4);
  int* csr_off3 = (int*)carve((size_t)3 * (N + 1) * 4);
  int* cursor3 = (int*)carve((size_t)3 * N * 4);
  int* csr_src3 = (int*)carve((size_t)3 * E * 4);
  float* csr_w3 = (float*)carve((size_t)3 * E * 4);
  unsigned short* x1 = (unsigned short*)carve((size_t)N * H1 * 2);  // also x2, fused
  unsigned short* h1 = (unsigned short*)carve((size_t)N * H1 * 2);
  unsigned short* comb = (unsigned short*)carve((size_t)N * CH * 2);
  unsigned short* x2 = x1;
  unsigned short* fused = x1;

  const int gx = (N + 63) / 64;    // 782
  const int nb = (N + 255) / 256;  // 196
  const int eb = (E + 255) / 256;  // 2344

  // ---- one fused transpose for all weights ----
  TransArgs ta;
  int base = 0;
  const float* wsrc[7] = {(const float*)d_in[3],  (const float*)d_in[10], (const float*)d_in[17],
                          (const float*)d_in[5],  (const float*)d_in[12], (const float*)d_in[19],
                          (const float*)d_in[21]};
  unsigned short* wdst[7] = {w1t[0], w1t[1], w1t[2], w2t[0], w2t[1], w2t[2], wft};
  int wK[7] = {1000, 1000, 500, 128, 128, 128, 192};
  int wN[7] = {128, 128, 128, 64, 64, 64, 64};
  int wKp[7] = {1024, 1024, 512, 128, 128, 128, 192};
  for (int s = 0; s < 7; ++s) {
    ta.d[s] = {wsrc[s], wdst[s], wK[s], wN[s], wKp[s], base};
    base += wN[s] * wKp[s];
  }
  ta.total = base;
  transpose_all_kernel<<<(base + 255) / 256, 256, 0, stream>>>(ta);

  // ---- batched CSR build for all 3 branches ----
  EdgeArgs ea;
  for (int b = 0; b < 3; ++b) {
    ea.ei[b] = (const int*)d_in[b * 7 + 1];
    ea.ew[b] = (const float*)d_in[b * 7 + 2];
  }
  hipMemsetAsync(deg3, 0, (size_t)3 * N * 4, stream);
  hipMemsetAsync(cnt3, 0, (size_t)3 * N * 4, stream);
  deg_cnt_kernel<<<3 * eb, 256, 0, stream>>>(ea, deg3, cnt3, E, eb);
  dinv_kernel<<<(3 * N + 255) / 256, 256, 0, stream>>>(deg3, dinv3, 3 * N);
  scan1_kernel<<<3 * nb, 256, 0, stream>>>(cnt3, partial3, bsums3, N, nb);
  scan2_kernel<<<3, 256, 0, stream>>>(bsums3, nb);
  scan3_kernel<<<3 * nb, 256, 0, stream>>>(partial3, cnt3, bsums3, csr_off3, cursor3, N, E, nb);
  bucket_kernel<<<3 * eb, 256, 0, stream>>>(ea, dinv3, cursor3, csr_src3, csr_w3, E, eb);

  // ---- per-branch pipeline ----
  for (int b = 0; b < 3; ++b) {
    const float* feat = (const float*)d_in[b * 7 + 0];
    const float* b1 = (const float*)d_in[b * 7 + 4];
    const float* b2 = (const float*)d_in[b * 7 + 6];
    const float* dinv = dinv3 + (size_t)b * N;
    const int* off = csr_off3 + (size_t)b * (N + 1);
    const int* src = csr_src3 + (size_t)b * E;
    const float* cw = csr_w3 + (size_t)b * E;

    gemm_kernel<128, false, true, false><<<gx, 256, 0, stream>>>(feat, w1t[b], nullptr, x1, N,
                                                                 Ds[b], kpad1[b], H1);
    agg128_kernel<<<(N + 3) / 4, 256, 0, stream>>>(x1, dinv, off, src, cw, b1, h1, N);
    gemm_kernel<64, true, true, false><<<gx, 256, 0, stream>>>(h1, w2t[b], nullptr, x2, N, 128,
                                                               128, H2);
    agg64_kernel<<<(N + 3) / 4, 256, 0, stream>>>(x2, dinv, off, src, cw, b2, comb, CH, b * 64, N);
  }

  gemm_kernel<64, true, true, true><<<gx, 256, 0, stream>>>(comb, wft, (const float*)d_in[22],
                                                            fused, N, CH, CH, H2);
  pred_kernel<<<nb, 256, 0, stream>>>(fused, (const float*)d_in[23], (const float*)d_in[24],
                                      (float*)d_out, N);
}

// Round 3
// 645.422 us; speedup vs baseline: 1.6430x; 1.3055x over previous
//
#include <hip/hip_runtime.h>
#include <hip/hip_bf16.h>

typedef __attribute__((ext_vector_type(8))) short short8;
typedef __attribute__((ext_vector_type(4))) float f32x4;
typedef unsigned long long ull;

#define NN 50000
#define NE 600000

__device__ __forceinline__ unsigned short f32_bf16(float f) {
  unsigned u = __float_as_uint(f);
  unsigned r = u + 0x7FFFu + ((u >> 16) & 1u);
  return (unsigned short)(r >> 16);
}
__device__ __forceinline__ float bf_lo(unsigned v) { return __uint_as_float(v << 16); }
__device__ __forceinline__ float bf_hi(unsigned v) { return __uint_as_float(v & 0xFFFF0000u); }

// ---------------- fused transpose of all 7 weights: W[K][N] f32 -> WT[N][Kpad] bf16 ----
struct TransDesc { const float* src; unsigned short* dst; int K, Nn, Kpad, base; };
struct TransArgs { TransDesc d[7]; int total; };

__global__ void transpose_all_kernel(TransArgs a) {
  int idx = blockIdx.x * 256 + threadIdx.x;
  if (idx >= a.total) return;
  int s = 0;
#pragma unroll
  for (int q = 1; q < 7; ++q)
    if (idx >= a.d[q].base) s = q;
  TransDesc t = a.d[s];
  int off = idx - t.base;
  int n = off / t.Kpad, k = off % t.Kpad;
  float v = (k < t.K) ? t.src[(size_t)k * t.Nn + n] : 0.f;
  t.dst[off] = f32_bf16(v);
}

// ---------------- GEMM body (bf16 MFMA, BM=64, register prefetch) ----------------
template <int BN, bool ABF16, bool CBF16, bool EPI>
__device__ __forceinline__ void gemm_body(const void* __restrict__ Av,
                                          const unsigned short* __restrict__ BT,
                                          const float* __restrict__ bias, void* __restrict__ Cv,
                                          int M, int K, int Kpad, int ldc, int bx) {
  constexpr int BM = 64, BK = 32, LW = BK + 8;
  __shared__ __align__(16) unsigned short As[BM * LW];
  __shared__ __align__(16) unsigned short Bs[BN * LW];
  const int tid = threadIdx.x;
  const int m0 = bx * BM;
  const int wid = tid >> 6, lane = tid & 63;
  constexpr int WC = (BN == 128) ? 2 : 1;
  constexpr int WTM = (BN == 128) ? 32 : 16;
  constexpr int FM = WTM / 16;
  constexpr int FN = 4;
  const int wr = wid / WC, wc = wid % WC;
  const int rowbase = wr * WTM, colbase = wc * 64;
  const int lrow = lane & 15, lk = lane >> 4;

  const float* Af = (const float*)Av;
  const unsigned short* Ah = (const unsigned short*)Av;

  f32x4 acc[FM][FN] = {};
  float4 arf[2];
  short8 arh;
  short8 brr[BN / 64];

  const int nt = Kpad / BK;

  auto loadA = [&](int k0) {
    if (ABF16) {
      int row = tid >> 2, c8 = tid & 3;
      int gr = m0 + row;
      if (gr >= M) gr = M - 1;
      arh = *(const short8*)(Ah + (size_t)gr * K + k0 + c8 * 8);
    } else {
#pragma unroll
      for (int p = 0; p < 2; ++p) {
        int f = tid + p * 256;
        int row = f >> 3, c4 = f & 7;
        int gr = m0 + row;
        if (gr >= M) gr = M - 1;
        int gk = k0 + c4 * 4;
        float4 v = make_float4(0.f, 0.f, 0.f, 0.f);
        const float* base = Af + (size_t)gr * K + gk;
        if (gk + 4 <= K) {
          v = *(const float4*)base;
        } else {
          if (gk + 0 < K) v.x = base[0];
          if (gk + 1 < K) v.y = base[1];
          if (gk + 2 < K) v.z = base[2];
          if (gk + 3 < K) v.w = base[3];
        }
        arf[p] = v;
      }
    }
  };
  auto loadB = [&](int k0) {
#pragma unroll
    for (int p = 0; p < BN / 64; ++p) {
      int f = tid + p * 256;
      int n = f >> 2, c8 = f & 3;
      brr[p] = *(const short8*)(BT + (size_t)n * Kpad + k0 + c8 * 8);
    }
  };
  auto storeAB = [&]() {
    if (ABF16) {
      int row = tid >> 2, c8 = tid & 3;
      *reinterpret_cast<short8*>(&As[row * LW + c8 * 8]) = arh;
    } else {
#pragma unroll
      for (int p = 0; p < 2; ++p) {
        int f = tid + p * 256;
        int row = f >> 3, c4 = f & 7;
        unsigned a0 = (unsigned)f32_bf16(arf[p].x) | ((unsigned)f32_bf16(arf[p].y) << 16);
        unsigned a1 = (unsigned)f32_bf16(arf[p].z) | ((unsigned)f32_bf16(arf[p].w) << 16);
        *reinterpret_cast<uint2*>(&As[row * LW + c4 * 4]) = make_uint2(a0, a1);
      }
    }
#pragma unroll
    for (int p = 0; p < BN / 64; ++p) {
      int f = tid + p * 256;
      int n = f >> 2, c8 = f & 3;
      *reinterpret_cast<short8*>(&Bs[n * LW + c8 * 8]) = brr[p];
    }
  };

  loadA(0);
  loadB(0);
  for (int kt = 0; kt < nt; ++kt) {
    if (kt) __syncthreads();
    storeAB();
    __syncthreads();
    if (kt + 1 < nt) {
      loadA((kt + 1) * BK);
      loadB((kt + 1) * BK);
    }
    short8 af[FM], bf[FN];
#pragma unroll
    for (int i = 0; i < FM; ++i)
      af[i] = *reinterpret_cast<const short8*>(&As[(rowbase + i * 16 + lrow) * LW + lk * 8]);
#pragma unroll
    for (int j = 0; j < FN; ++j)
      bf[j] = *reinterpret_cast<const short8*>(&Bs[(colbase + j * 16 + lrow) * LW + lk * 8]);
#pragma unroll
    for (int i = 0; i < FM; ++i)
#pragma unroll
      for (int j = 0; j < FN; ++j)
        acc[i][j] = __builtin_amdgcn_mfma_f32_16x16x32_bf16(af[i], bf[j], acc[i][j], 0, 0, 0);
  }

#pragma unroll
  for (int i = 0; i < FM; ++i) {
#pragma unroll
    for (int j = 0; j < FN; ++j) {
#pragma unroll
      for (int q = 0; q < 4; ++q) {
        int row = m0 + rowbase + i * 16 + lk * 4 + q;
        int col = colbase + j * 16 + lrow;
        if (row < M) {
          float v = acc[i][j][q];
          if (EPI) v = fmaxf(v + bias[col], 0.f);
          if (CBF16)
            ((unsigned short*)Cv)[(size_t)row * ldc + col] = f32_bf16(v);
          else
            ((float*)Cv)[(size_t)row * ldc + col] = v;
        }
      }
    }
  }
}

template <int BN, bool ABF16, bool CBF16, bool EPI>
__global__ __launch_bounds__(256) void gemm_kernel(const void* __restrict__ Av,
                                                   const unsigned short* __restrict__ BT,
                                                   const float* __restrict__ bias,
                                                   void* __restrict__ Cv, int M, int K, int Kpad,
                                                   int ldc) {
  gemm_body<BN, ABF16, CBF16, EPI>(Av, BT, bias, Cv, M, K, Kpad, ldc, blockIdx.x);
}

// ---------------- mega kernels: GEMM blocks + edge-processing blocks ----------------
struct EdgeArgs { const int* ei[3]; const float* ew[3]; };
struct MegaArgs {
  EdgeArgs ea;
  ull* pc;                  // packed (count<<32 | fix24 wsum) per node per branch
  unsigned short* rank;     // per-edge within-node rank
  int* off3;                // CSR start offsets
  float* dinv3;
  int2* csr;                // {src, norm-as-float-bits}
  const float* feat;        // GEMM role inputs
  const unsigned short* BT;
  unsigned short* X;
  int K, Kpad, GB, FB;
};

template <int MODE>  // 0 = count, 1 = scatter
__global__ __launch_bounds__(256) void mega_kernel(MegaArgs a) {
  if ((int)blockIdx.x < a.GB) {
    gemm_body<128, false, true, false>(a.feat, a.BT, nullptr, a.X, NN, a.K, a.Kpad, 128,
                                       blockIdx.x);
    return;
  }
  const int stride = a.FB * 256;
  for (int idx = (blockIdx.x - a.GB) * 256 + threadIdx.x; idx < 3 * NE; idx += stride) {
    int b = idx / NE, e = idx - b * NE;
    const int* ei = a.ea.ei[b];
    int d = ei[NE + e];
    float w = a.ea.ew[b][e];
    if (MODE == 0) {
      ull pkt = (1ull << 32) | (ull)(unsigned)(w * 16777216.0f);
      ull old = atomicAdd(&a.pc[b * NN + d], pkt);
      a.rank[idx] = (unsigned short)(old >> 32);
    } else {
      int s = ei[e];
      int t = a.off3[b * NN + d] + (int)a.rank[idx];
      float cw = a.dinv3[b * NN + s] * w * a.dinv3[b * NN + d];
      a.csr[(size_t)b * NE + t] = make_int2(s, __float_as_int(cw));
    }
  }
}

// ---------------- scans over pc counts ----------------
__global__ void scan1_kernel(const ull* __restrict__ pc, int* __restrict__ partial3,
                             int* __restrict__ bsums3, int n, int bpb) {
  __shared__ int sd[256];
  int b = blockIdx.x / bpb, blk = blockIdx.x % bpb;
  int i = blk * 256 + threadIdx.x;
  int v = (i < n) ? (int)(pc[b * NN + i] >> 32) : 0;
  sd[threadIdx.x] = v;
  __syncthreads();
  for (int o = 1; o < 256; o <<= 1) {
    int t = (threadIdx.x >= o) ? sd[threadIdx.x - o] : 0;
    __syncthreads();
    sd[threadIdx.x] += t;
    __syncthreads();
  }
  if (i < n) partial3[b * NN + i] = sd[threadIdx.x];
  if (threadIdx.x == 255) bsums3[b * 256 + blk] = sd[255];
}

__global__ void scan2_kernel(int* __restrict__ bsums3, int nb) {
  __shared__ int sd[256];
  int b = blockIdx.x;
  int v = (threadIdx.x < nb) ? bsums3[b * 256 + threadIdx.x] : 0;
  sd[threadIdx.x] = v;
  __syncthreads();
  for (int o = 1; o < 256; o <<= 1) {
    int t = (threadIdx.x >= o) ? sd[threadIdx.x - o] : 0;
    __syncthreads();
    sd[threadIdx.x] += t;
    __syncthreads();
  }
  if (threadIdx.x < nb) bsums3[b * 256 + threadIdx.x] = sd[threadIdx.x] - v;
}

__global__ void scan3_kernel(const ull* __restrict__ pc, const int* __restrict__ partial3,
                             const int* __restrict__ bsums3, int* __restrict__ off3,
                             float* __restrict__ dinv3, int n, int bpb) {
  int b = blockIdx.x / bpb, blk = blockIdx.x % bpb;
  int i = blk * 256 + threadIdx.x;
  if (i >= n) return;
  ull p = pc[b * NN + i];
  int c = (int)(p >> 32);
  off3[b * NN + i] = partial3[b * NN + i] - c + bsums3[b * 256 + blk];
  float deg = (float)(unsigned)(p & 0xFFFFFFFFull) * (1.0f / 16777216.0f) + 1.0f;
  dinv3[b * NN + i] = rsqrtf(deg);
}

// ---------------- CSR gather aggregation, bf16 in / bf16 out, bias+relu ----------------
__global__ void agg128_kernel(const unsigned short* __restrict__ x, const float* __restrict__ dinv,
                              const int* __restrict__ off, const ull* __restrict__ pc,
                              const int2* __restrict__ csr, const float* __restrict__ bias,
                              unsigned short* __restrict__ out, int n) {
  int i = blockIdx.x * 4 + (threadIdx.x >> 6);
  if (i >= n) return;
  int lane = threadIdx.x & 63;
  float di = dinv[i];
  unsigned sv = *(const unsigned*)(x + (size_t)i * 128 + lane * 2);
  float w0 = di * di;
  float acc0 = bf_lo(sv) * w0, acc1 = bf_hi(sv) * w0;
  int s = off[i];
  int e = s + (int)(pc[i] >> 32);
  for (int t = s; t < e; ++t) {
    int2 sl = csr[t];
    float wt = __int_as_float(sl.y);
    unsigned v = *(const unsigned*)(x + (size_t)sl.x * 128 + lane * 2);
    acc0 += bf_lo(v) * wt;
    acc1 += bf_hi(v) * wt;
  }
  acc0 = fmaxf(acc0 + bias[lane * 2], 0.f);
  acc1 = fmaxf(acc1 + bias[lane * 2 + 1], 0.f);
  unsigned o = (unsigned)f32_bf16(acc0) | ((unsigned)f32_bf16(acc1) << 16);
  *(unsigned*)(out + (size_t)i * 128 + lane * 2) = o;
}

__global__ void agg64_kernel(const unsigned short* __restrict__ x, const float* __restrict__ dinv,
                             const int* __restrict__ off, const ull* __restrict__ pc,
                             const int2* __restrict__ csr, const float* __restrict__ bias,
                             unsigned short* __restrict__ out, int ldo, int coff, int n) {
  int i = blockIdx.x * 4 + (threadIdx.x >> 6);
  if (i >= n) return;
  int lane = threadIdx.x & 63;
  int half = lane >> 5, l2 = (lane & 31) * 2;
  float acc0 = 0.f, acc1 = 0.f;
  if (half == 0) {
    float di = dinv[i];
    unsigned sv = *(const unsigned*)(x + (size_t)i * 64 + l2);
    float w0 = di * di;
    acc0 = bf_lo(sv) * w0;
    acc1 = bf_hi(sv) * w0;
  }
  int s = off[i];
  int e = s + (int)(pc[i] >> 32);
  for (int t = s + half; t < e; t += 2) {
    int2 sl = csr[t];
    float wt = __int_as_float(sl.y);
    unsigned v = *(const unsigned*)(x + (size_t)sl.x * 64 + l2);
    acc0 += bf_lo(v) * wt;
    acc1 += bf_hi(v) * wt;
  }
  acc0 += __shfl_xor(acc0, 32);
  acc1 += __shfl_xor(acc1, 32);
  if (half == 0) {
    acc0 = fmaxf(acc0 + bias[l2], 0.f);
    acc1 = fmaxf(acc1 + bias[l2 + 1], 0.f);
    unsigned o = (unsigned)f32_bf16(acc0) | ((unsigned)f32_bf16(acc1) << 16);
    *(unsigned*)(out + (size_t)i * ldo + coff + l2) = o;
  }
}

// ---------------- pred ----------------
__global__ void pred_kernel(const unsigned short* __restrict__ fused, const float* __restrict__ Wp,
                            const float* __restrict__ bp, float* __restrict__ out, int n) {
  __shared__ float ws_[128];
  __shared__ float bs_[2];
  if (threadIdx.x < 128) ws_[threadIdx.x] = Wp[threadIdx.x];
  if (threadIdx.x < 2) bs_[threadIdx.x] = bp[threadIdx.x];
  __syncthreads();
  int i = blockIdx.x * 256 + threadIdx.x;
  if (i >= n) return;
  float a0 = bs_[0], a1 = bs_[1];
  const uint2* row = reinterpret_cast<const uint2*>(fused + (size_t)i * 64);
#pragma unroll
  for (int q = 0; q < 16; ++q) {
    uint2 u = row[q];
    float f0 = bf_lo(u.x), f1 = bf_hi(u.x), f2 = bf_lo(u.y), f3 = bf_hi(u.y);
    int k = q * 4;
    a0 += f0 * ws_[k * 2] + f1 * ws_[(k + 1) * 2] + f2 * ws_[(k + 2) * 2] + f3 * ws_[(k + 3) * 2];
    a1 += f0 * ws_[k * 2 + 1] + f1 * ws_[(k + 1) * 2 + 1] + f2 * ws_[(k + 2) * 2 + 1] +
          f3 * ws_[(k + 3) * 2 + 1];
  }
  out[(size_t)i * 2 + 0] = a0;
  out[(size_t)i * 2 + 1] = a1;
}

extern "C" void kernel_launch(void* const* d_in, const int* in_sizes, int n_in, void* d_out,
                              int out_size, void* d_ws, size_t ws_size, hipStream_t stream) {
  const int N = NN, E = NE;
  const int Ds[3] = {1000, 1000, 500};
  const int H1 = 128, H2 = 64, CH = 192;

  char* p = (char*)d_ws;
  auto carve = [&](size_t bytes) {
    void* r = (void*)p;
    p += (bytes + 255) & ~(size_t)255;
    return r;
  };

  unsigned short* w1t[3];
  int kpad1[3];
  for (int b = 0; b < 3; ++b) {
    kpad1[b] = (Ds[b] + 31) & ~31;
    w1t[b] = (unsigned short*)carve((size_t)H1 * kpad1[b] * 2);
  }
  unsigned short* w2t[3];
  for (int b = 0; b < 3; ++b) w2t[b] = (unsigned short*)carve((size_t)H2 * 128 * 2);
  unsigned short* wft = (unsigned short*)carve((size_t)H2 * 192 * 2);

  ull* pc = (ull*)carve((size_t)3 * N * 8);
  int* partial3 = (int*)carve((size_t)3 * N * 4);
  int* bsums3 = (int*)carve((size_t)3 * 256 * 4);
  int* off3 = (int*)carve((size_t)3 * N * 4);
  float* dinv3 = (float*)carve((size_t)3 * N * 4);
  unsigned short* rank = (unsigned short*)carve((size_t)3 * E * 2);
  int2* csr = (int2*)carve((size_t)3 * E * 8);
  unsigned short* x1a = (unsigned short*)carve((size_t)N * H1 * 2);
  unsigned short* x1b = (unsigned short*)carve((size_t)N * H1 * 2);
  unsigned short* h1 = (unsigned short*)carve((size_t)N * H1 * 2);
  unsigned short* comb = (unsigned short*)carve((size_t)N * CH * 2);

  const int gx = (N + 63) / 64;    // 782
  const int nb = (N + 255) / 256;  // 196
  const int FB = 2048;

  // ---- one fused transpose for all weights ----
  TransArgs ta;
  int base = 0;
  const float* wsrc[7] = {(const float*)d_in[3],  (const float*)d_in[10], (const float*)d_in[17],
                          (const float*)d_in[5],  (const float*)d_in[12], (const float*)d_in[19],
                          (const float*)d_in[21]};
  unsigned short* wdst[7] = {w1t[0], w1t[1], w1t[2], w2t[0], w2t[1], w2t[2], wft};
  int wK[7] = {1000, 1000, 500, 128, 128, 128, 192};
  int wN[7] = {128, 128, 128, 64, 64, 64, 64};
  int wKp[7] = {1024, 1024, 512, 128, 128, 128, 192};
  for (int s = 0; s < 7; ++s) {
    ta.d[s] = {wsrc[s], wdst[s], wK[s], wN[s], wKp[s], base};
    base += wN[s] * wKp[s];
  }
  ta.total = base;
  transpose_all_kernel<<<(base + 255) / 256, 256, 0, stream>>>(ta);

  hipMemsetAsync(pc, 0, (size_t)3 * N * 8, stream);

  MegaArgs ma;
  for (int b = 0; b < 3; ++b) {
    ma.ea.ei[b] = (const int*)d_in[b * 7 + 1];
    ma.ea.ew[b] = (const float*)d_in[b * 7 + 2];
  }
  ma.pc = pc;
  ma.rank = rank;
  ma.off3 = off3;
  ma.dinv3 = dinv3;
  ma.csr = csr;
  ma.GB = gx;
  ma.FB = FB;

  // ---- megaA: count (all branches) + GEMM1(branch 0) ----
  ma.feat = (const float*)d_in[0];
  ma.BT = w1t[0];
  ma.X = x1a;
  ma.K = Ds[0];
  ma.Kpad = kpad1[0];
  mega_kernel<0><<<gx + FB, 256, 0, stream>>>(ma);

  scan1_kernel<<<3 * nb, 256, 0, stream>>>(pc, partial3, bsums3, N, nb);
  scan2_kernel<<<3, 256, 0, stream>>>(bsums3, nb);
  scan3_kernel<<<3 * nb, 256, 0, stream>>>(pc, partial3, bsums3, off3, dinv3, N, nb);

  // ---- megaB: scatter (all branches) + GEMM1(branch 1) ----
  ma.feat = (const float*)d_in[7];
  ma.BT = w1t[1];
  ma.X = x1b;
  ma.K = Ds[1];
  ma.Kpad = kpad1[1];
  mega_kernel<1><<<gx + FB, 256, 0, stream>>>(ma);

  const int ab = (N + 3) / 4;

  // ---- branch 0 ----
  {
    const float* b1 = (const float*)d_in[4];
    const float* b2 = (const float*)d_in[6];
    agg128_kernel<<<ab, 256, 0, stream>>>(x1a, dinv3, off3, pc, csr, b1, h1, N);
    gemm_kernel<64, true, true, false><<<gx, 256, 0, stream>>>(h1, w2t[0], nullptr, x1a, N, 128,
                                                               128, H2);
    agg64_kernel<<<ab, 256, 0, stream>>>(x1a, dinv3, off3, pc, csr, b2, comb, CH, 0, N);
  }
  // gemm1 for branch 2 (x1a free after agg64 above)
  gemm_kernel<128, false, true, false><<<gx, 256, 0, stream>>>((const float*)d_in[14], w1t[2],
                                                               nullptr, x1a, N, Ds[2], kpad1[2],
                                                               H1);
  // ---- branch 1 ----
  {
    const float* b1 = (const float*)d_in[11];
    const float* b2 = (const float*)d_in[13];
    agg128_kernel<<<ab, 256, 0, stream>>>(x1b, dinv3 + N, off3 + N, pc + N, csr + (size_t)E, b1,
                                          h1, N);
    gemm_kernel<64, true, true, false><<<gx, 256, 0, stream>>>(h1, w2t[1], nullptr, x1b, N, 128,
                                                               128, H2);
    agg64_kernel<<<ab, 256, 0, stream>>>(x1b, dinv3 + N, off3 + N, pc + N, csr + (size_t)E, b2,
                                         comb, CH, 64, N);
  }
  // ---- branch 2 ----
  {
    const float* b1 = (const float*)d_in[18];
    const float* b2 = (const float*)d_in[20];
    agg128_kernel<<<ab, 256, 0, stream>>>(x1a, dinv3 + 2 * N, off3 + 2 * N, pc + 2 * N,
                                          csr + (size_t)2 * E, b1, h1, N);
    gemm_kernel<64, true, true, false><<<gx, 256, 0, stream>>>(h1, w2t[2], nullptr, x1a, N, 128,
                                                               128, H2);
    agg64_kernel<<<ab, 256, 0, stream>>>(x1a, dinv3 + 2 * N, off3 + 2 * N, pc + 2 * N,
                                         csr + (size_t)2 * E, b2, comb, CH, 128, N);
  }

  // ---- fusion + prediction ----
  gemm_kernel<64, true, true, true><<<gx, 256, 0, stream>>>(comb, wft, (const float*)d_in[22],
                                                            x1b, N, CH, CH, H2);
  pred_kernel<<<nb, 256, 0, stream>>>(x1b, (const float*)d_in[23], (const float*)d_in[24],
                                      (float*)d_out, N);
}